// Round 4
// baseline (346.373 us; speedup 1.0000x reference)
//
#include <hip/hip_runtime.h>
#include <cstdint>
#include <cstddef>

// ---------------------------------------------------------------------------
// Problem constants
// ---------------------------------------------------------------------------
#define BB    8      // batch
#define NH    12     // heads
#define BH    96     // BB*NH
#define SS    1024   // image tokens (32x32)
#define QQ    2048   // text tokens
#define DD    64     // head dim
#define HID   768
#define EDGE  32
#define KPOOL 16
#define POOLED 17

typedef short bf16x8 __attribute__((ext_vector_type(8)));
typedef _Float16 f16x8 __attribute__((ext_vector_type(8)));
typedef float f32x4  __attribute__((ext_vector_type(4)));

#define MFMA16B(a, b, c) __builtin_amdgcn_mfma_f32_16x16x32_bf16((a), (b), (c), 0, 0, 0)
#define MFMA16H(a, b, c) __builtin_amdgcn_mfma_f32_16x16x32_f16((a), (b), (c), 0, 0, 0)

// scores in base-2: Q pre-scaled by log2(e)/8 so exp(s/8) == exp2(score2)
#define QSCALE 0.18033688011112042f

#if __has_builtin(__builtin_amdgcn_exp2f)
#define EXP2(x) __builtin_amdgcn_exp2f(x)
#else
#define EXP2(x) exp2f(x)
#endif

__device__ __forceinline__ short f2bf(float x) {
    unsigned u = __builtin_bit_cast(unsigned, x);
    u = u + 0x7fffu + ((u >> 16) & 1u);          // RNE
    return (short)(u >> 16);
}
__device__ __forceinline__ short f2h(float x) {
    _Float16 h = (_Float16)x;                    // RNE
    return __builtin_bit_cast(short, h);
}
__device__ __forceinline__ float h2f(short h) {
    return (float)__builtin_bit_cast(_Float16, h);
}
__device__ __forceinline__ f16x8 ash(bf16x8 v) {
    return __builtin_bit_cast(f16x8, v);
}

// ---------------------------------------------------------------------------
// Fragment-order layout for Qs/Ks (fp16 hi/lo — fp16 products are exact in the
// f32 MFMA accumulator, so 3-term hi/lo has ~2^-23 effective score error):
//   rows grouped by 16 (group g, row-in-group c). Per group: 2048 shorts =
//   4 chunks of 512: ch0=hi,k[0:32) ch1=hi,k[32:64) ch2=lo,k[0:32) ch3=lo,k[32:64)
//   chunk internal: [quad(4)][c(16)][j(8)]  -> frag read = base + lane*8 shorts
// ---------------------------------------------------------------------------

// K0a: cast text -> Qs fragment-order (scaled by QSCALE), fp16 hi/lo
__global__ __launch_bounds__(256) void k_castq(const float* __restrict__ txt,
                                               short* __restrict__ Qs) {
    int i = blockIdx.x * 256 + threadIdx.x;
    int quad = i & 3, kh = (i >> 2) & 1;
    int row = i >> 3;                    // bh*2048 + q
    int c = row & 15, g = row >> 4;
    int q = row & 2047, bh = row >> 11;
    int b = bh / NH, h = bh - b * NH;
    const float* sp = txt + ((size_t)b * QQ + q) * HID + h * DD + kh * 32 + quad * 8;
    bf16x8 vh, vl;
#pragma unroll
    for (int j = 0; j < 8; j++) {
        float x = sp[j] * QSCALE;
        _Float16 hi = (_Float16)x;
        vh[j] = __builtin_bit_cast(short, hi);
        vl[j] = f2h(x - (float)hi);
    }
    short* dp = Qs + (size_t)g * 2048 + kh * 512 + quad * 128 + c * 8;
    *(bf16x8*)dp = vh;
    *(bf16x8*)(dp + 1024) = vl;
}

// K0b: cast image -> Ks fragment-order (unscaled), fp16 hi/lo
__global__ __launch_bounds__(256) void k_castk(const float* __restrict__ img,
                                               short* __restrict__ Ks) {
    int i = blockIdx.x * 256 + threadIdx.x;
    int quad = i & 3, kh = (i >> 2) & 1;
    int row = i >> 3;                    // bh*1024 + s
    int c = row & 15, g = row >> 4;
    int s = row & 1023, bh = row >> 10;
    int b = bh / NH, h = bh - b * NH;
    const float* sp = img + ((size_t)b * SS + s) * HID + h * DD + kh * 32 + quad * 8;
    bf16x8 vh, vl;
#pragma unroll
    for (int j = 0; j < 8; j++) {
        float x = sp[j];
        _Float16 hi = (_Float16)x;
        vh[j] = __builtin_bit_cast(short, hi);
        vl[j] = f2h(x - (float)hi);
    }
    short* dp = Ks + (size_t)g * 2048 + kh * 512 + quad * 128 + c * 8;
    *(bf16x8*)dp = vh;
    *(bf16x8*)(dp + 1024) = vl;
}

// K0c: blocks 0..143: W_in [k][n] -> transposed bf16 Wt [n][k].
//      block 144: W_up [64][256] -> bf16 B-fragment order Wupb:
//      addr = (n>>4)*1024 + (k>>5)*512 + ((k>>3)&3)*128 + (n&15)*8 + (k&7)
__global__ __launch_bounds__(256) void k_castw(const float* __restrict__ W,
                                               const float* __restrict__ Wup,
                                               short* __restrict__ Wt,
                                               short* __restrict__ Wupb) {
    if (blockIdx.x == 144) {
        for (int i = threadIdx.x; i < 16384; i += 256) {
            int k = i >> 8, n = i & 255;
            int addr = (n >> 4) * 1024 + (k >> 5) * 512 + ((k >> 3) & 3) * 128
                     + (n & 15) * 8 + (k & 7);
            Wupb[addr] = f2bf(Wup[k * 256 + n]);
        }
        return;
    }
    __shared__ float T[64][65];
    int bx = blockIdx.x % 12, by = blockIdx.x / 12;
    for (int i = threadIdx.x; i < 4096; i += 256) {
        int r = i >> 6, cc = i & 63;
        T[r][cc] = W[(size_t)(by * 64 + r) * HID + bx * 64 + cc];
    }
    __syncthreads();
    for (int i = threadIdx.x; i < 4096; i += 256) {
        int r = i >> 6, cc = i & 63;
        Wt[(size_t)(bx * 64 + r) * HID + by * 64 + cc] = f2bf(T[cc][r]);
    }
}

// ---------------------------------------------------------------------------
// K1: Lsum[bh][q] = sum_s exp2(score2)
// fp16 SINGLE-plane (hi chunks only): Lsum error is averaged over 1024 keys
// (relative error ~2e-5), far below argmax sensitivity. 2 MFMA per tile.
// launch_bounds (256,3): grid = 768 = 3 blocks/CU -> all resident, no tail.
// ---------------------------------------------------------------------------
__global__ __launch_bounds__(256, 3) void k_lsum(const short* __restrict__ Qs,
                                                 const short* __restrict__ Ks,
                                                 float* __restrict__ Lsum) {
    __shared__ short Kt[2][4096];
    int bh = blockIdx.x % BH;
    int qblk = blockIdx.x / BH;          // [0,8)
    int tid = threadIdx.x;
    int w = tid >> 6, lane = tid & 63;
    int quad = lane >> 4, c = lane & 15;

    f16x8 a0[4], a1[4];
    const short* qbase = Qs + (size_t)bh * QQ * 128;
#pragma unroll
    for (int t = 0; t < 4; t++) {
        const short* ap = qbase + (size_t)(qblk * 16 + w * 4 + t) * 2048 + lane * 8;
        a0[t] = ash(*(const bf16x8*)(ap));
        a1[t] = ash(*(const bf16x8*)(ap + 512));
    }
    f32x4 lacc[4];
#pragma unroll
    for (int t = 0; t < 4; t++) lacc[t] = (f32x4){0.f, 0.f, 0.f, 0.f};

    const short* kbase = Ks + (size_t)bh * SS * 128;
    int sg = tid >> 7, so = tid & 127;   // staging: 2 groups per j-step
    bf16x8 st[2];
#pragma unroll
    for (int j = 0; j < 2; j++)
        st[j] = *(const bf16x8*)(kbase + (size_t)(j * 2 + sg) * 2048 + so * 8);

    for (int t1 = 0; t1 < 16; t1++) {
        int buf = t1 & 1;
#pragma unroll
        for (int j = 0; j < 2; j++)
            *(bf16x8*)(&Kt[buf][j * 2048 + tid * 8]) = st[j];
        if (t1 + 1 < 16) {
#pragma unroll
            for (int j = 0; j < 2; j++)
                st[j] = *(const bf16x8*)(kbase + (size_t)((t1 + 1) * 4 + j * 2 + sg) * 2048 + so * 8);
        }
        __syncthreads();
#pragma unroll
        for (int g = 0; g < 4; g++) {
            const short* kp = &Kt[buf][g * 1024 + lane * 8];
            f16x8 kb0 = ash(*(const bf16x8*)(kp));
            f16x8 kb1 = ash(*(const bf16x8*)(kp + 512));
#pragma unroll
            for (int t = 0; t < 4; t++) {
                f32x4 acc = (f32x4){0.f, 0.f, 0.f, 0.f};
                acc = MFMA16H(a0[t], kb0, acc);
                acc = MFMA16H(a1[t], kb1, acc);
#pragma unroll
                for (int r = 0; r < 4; r++) lacc[t][r] += EXP2(acc[r]);
            }
        }
    }
#pragma unroll
    for (int t = 0; t < 4; t++) {
#pragma unroll
        for (int r = 0; r < 4; r++) {
            float v = lacc[t][r];
            v += __shfl_xor(v, 1);
            v += __shfl_xor(v, 2);
            v += __shfl_xor(v, 4);
            v += __shfl_xor(v, 8);
            if (c == 0)
                Lsum[(size_t)bh * QQ + qblk * 256 + w * 64 + t * 16 + quad * 4 + r] = v;
        }
    }
}

// ---------------------------------------------------------------------------
// K2: iattn[bh][s] += sum_{q half} exp2(score2)/Lsum[q]
// fp16 hi/lo 3-term (6 MFMA) — exact fp16 products => ~fp32-accurate scores.
// launch_bounds (256,3): 3 blocks/CU resident (96 KB LDS <= 160), no tail.
// ---------------------------------------------------------------------------
__global__ __launch_bounds__(256, 3) void k_attnacc(const short* __restrict__ Qs,
                                                    const short* __restrict__ Ks,
                                                    const float* __restrict__ Lsum,
                                                    float* __restrict__ iattn) {
    __shared__ short Qt[2][8192];
    int bh = blockIdx.x % BH;
    int rem = blockIdx.x / BH;           // [0,8)
    int sblk = rem >> 1, qh = rem & 1;
    int tid = threadIdx.x;
    int w = tid >> 6, lane = tid & 63;
    int quad = lane >> 4, c = lane & 15;

    f16x8 ah0[4], ah1[4], al0[4], al1[4];
    const short* kbase = Ks + (size_t)bh * SS * 128;
#pragma unroll
    for (int t = 0; t < 4; t++) {
        const short* ap = kbase + (size_t)(sblk * 16 + w * 4 + t) * 2048 + lane * 8;
        ah0[t] = ash(*(const bf16x8*)(ap));
        ah1[t] = ash(*(const bf16x8*)(ap + 512));
        al0[t] = ash(*(const bf16x8*)(ap + 1024));
        al1[t] = ash(*(const bf16x8*)(ap + 1536));
    }
    f32x4 racc[4];
#pragma unroll
    for (int t = 0; t < 4; t++) racc[t] = (f32x4){0.f, 0.f, 0.f, 0.f};

    const short* qbase = Qs + ((size_t)bh * QQ + qh * 1024) * 128;
    const float* lbase = Lsum + (size_t)bh * QQ + qh * 1024;

    bf16x8 st[4];
#pragma unroll
    for (int j = 0; j < 4; j++)
        st[j] = *(const bf16x8*)(qbase + (size_t)j * 2048 + tid * 8);

    for (int t2 = 0; t2 < 16; t2++) {
        int buf = t2 & 1;
#pragma unroll
        for (int j = 0; j < 4; j++)
            *(bf16x8*)(&Qt[buf][j * 2048 + tid * 8]) = st[j];
        if (t2 + 1 < 16) {
#pragma unroll
            for (int j = 0; j < 4; j++)
                st[j] = *(const bf16x8*)(qbase + (size_t)(t2 + 1) * 8192 + j * 2048 + tid * 8);
        }
        __syncthreads();
        float rl[4];
#pragma unroll
        for (int g = 0; g < 4; g++)
            rl[g] = __builtin_amdgcn_rcpf(lbase[t2 * 64 + g * 16 + c]);
#pragma unroll
        for (int g = 0; g < 4; g++) {
            const short* qp = &Qt[buf][g * 2048 + lane * 8];
            f16x8 qb0 = ash(*(const bf16x8*)(qp));
            f16x8 qb1 = ash(*(const bf16x8*)(qp + 512));
            f16x8 qb2 = ash(*(const bf16x8*)(qp + 1024));
            f16x8 qb3 = ash(*(const bf16x8*)(qp + 1536));
#pragma unroll
            for (int t = 0; t < 4; t++) {
                f32x4 acc = (f32x4){0.f, 0.f, 0.f, 0.f};
                acc = MFMA16H(ah0[t], qb0, acc);
                acc = MFMA16H(ah1[t], qb1, acc);
                acc = MFMA16H(al0[t], qb0, acc);
                acc = MFMA16H(al1[t], qb1, acc);
                acc = MFMA16H(ah0[t], qb2, acc);
                acc = MFMA16H(ah1[t], qb3, acc);
#pragma unroll
                for (int r = 0; r < 4; r++)
                    racc[t][r] = fmaf(EXP2(acc[r]), rl[g], racc[t][r]);
            }
        }
    }
#pragma unroll
    for (int t = 0; t < 4; t++) {
#pragma unroll
        for (int r = 0; r < 4; r++) {
            float v = racc[t][r];
            v += __shfl_xor(v, 1);
            v += __shfl_xor(v, 2);
            v += __shfl_xor(v, 4);
            v += __shfl_xor(v, 8);
            if (c == 0)
                atomicAdd(&iattn[(size_t)bh * SS + sblk * 256 + w * 64 + t * 16 + quad * 4 + r], v);
        }
    }
}

// ---------------------------------------------------------------------------
// K4: fused pool+argmax+region-gather+upsample GEMM (MFMA) + pixel-shuffle.
// grid: bh(96) x nq(4 oc-quarters). Block: pool argmax from iattn (redundant
// per nq — cheap), then region [256 pos x 64 d] staged bf16 A-frag order in
// LDS, W_up from Wupb B-frags, MFMA -> Xb bf16.
// ---------------------------------------------------------------------------
__global__ __launch_bounds__(256, 2) void k_up(const float* __restrict__ img,
                                               const float* __restrict__ iattn,
                                               const short* __restrict__ Wupb,
                                               short* __restrict__ Xb) {
    __shared__ short Reg[16384];         // 32 KB, aliased for pool phase
    float* F = (float*)Reg;
    float* Apool = F;                    // [1024]
    float* Vp = F + 1024;                // [544]
    float* bvp = F + 1568;               // [256]
    int*   bip = (int*)(F + 1824);       // [256]

    int bh = blockIdx.x >> 2, nq = blockIdx.x & 3;
    int b = bh / NH, h = bh - b * NH;
    int tid = threadIdx.x;
    int w = tid >> 6, lane = tid & 63;
    int quad = lane >> 4, c = lane & 15;

    // ---- pool + argmax (np first-max tiebreak) ----
    for (int i = tid; i < 1024; i += 256) Apool[i] = iattn[(size_t)bh * SS + i];
    __syncthreads();
    for (int i = tid; i < POOLED * EDGE; i += 256) {
        int r = i >> 5, cc = i & 31;
        float s = 0.f;
#pragma unroll
        for (int k = 0; k < KPOOL; k++) s += Apool[(r + k) * EDGE + cc];
        Vp[i] = s;
    }
    __syncthreads();
    float best = -1e30f;
    int bidx = 1 << 30;
    for (int i = tid; i < POOLED * POOLED; i += 256) {
        int r = i / POOLED, cc = i - r * POOLED;
        float s = 0.f;
#pragma unroll
        for (int k = 0; k < KPOOL; k++) s += Vp[r * EDGE + cc + k];
        if (s > best || (s == best && i < bidx)) { best = s; bidx = i; }
    }
    bvp[tid] = best;
    bip[tid] = bidx;
    __syncthreads();
    for (int off = 128; off; off >>= 1) {
        if (tid < off) {
            float ov = bvp[tid + off];
            int oi = bip[tid + off];
            if (ov > bvp[tid] || (ov == bvp[tid] && oi < bip[tid])) {
                bvp[tid] = ov;
                bip[tid] = oi;
            }
        }
        __syncthreads();
    }
    int widx = bip[0];
    __syncthreads();                     // all reads done before staging overwrites
    int r0 = widx / POOLED, c0 = widx - r0 * POOLED;

    // ---- stage region bf16 in A-fragment order ----
    // LDS addr for (pos,d): (pos>>4)*1024 + (d>>5)*512 + ((d>>3)&3)*128 + (pos&15)*8 + (d&7)
    for (int p = tid; p < 2048; p += 256) {
        int pos = p >> 3, sub = p & 7;   // sub -> d = sub*8..sub*8+7
        int gi = r0 + (pos >> 4), gj = c0 + (pos & 15);
        const float* sp = img + ((size_t)b * SS + gi * EDGE + gj) * HID + h * DD + sub * 8;
        bf16x8 v;
#pragma unroll
        for (int j = 0; j < 8; j++) v[j] = f2bf(sp[j]);
        *(bf16x8*)(&Reg[(pos >> 4) * 1024 + (sub >> 2) * 512 + (sub & 3) * 128 + (pos & 15) * 8]) = v;
    }
    __syncthreads();

    // ---- B-fragments (this block's 64 oc = 4 n-tiles) ----
    bf16x8 bu[4][2];
#pragma unroll
    for (int u = 0; u < 4; u++) {
#pragma unroll
        for (int kh = 0; kh < 2; kh++)
            bu[u][kh] = *(const bf16x8*)(Wupb + (nq * 4 + u) * 1024 + kh * 512 + lane * 8);
    }

    // ---- MFMA + pixel-shuffle epilogue ----
#pragma unroll
    for (int t = 0; t < 4; t++) {
        int g = w * 4 + t;               // pos group [0,16)
        bf16x8 a0 = *(const bf16x8*)(&Reg[g * 1024 + lane * 8]);
        bf16x8 a1 = *(const bf16x8*)(&Reg[g * 1024 + 512 + lane * 8]);
#pragma unroll
        for (int u = 0; u < 4; u++) {
            f32x4 acc = (f32x4){0.f, 0.f, 0.f, 0.f};
            acc = MFMA16B(a0, bu[u][0], acc);
            acc = MFMA16B(a1, bu[u][1], acc);
#pragma unroll
            for (int r = 0; r < 4; r++) {
                int pos = g * 16 + quad * 4 + r;
                int oc = nq * 64 + u * 16 + c;
                int i16 = pos >> 4, j16 = pos & 15;
                int a = oc >> 7, bbit = (oc >> 6) & 1, dp = oc & 63;
                int p2 = (2 * i16 + a) * EDGE + (2 * j16 + bbit);
                Xb[((size_t)b * SS + p2) * HID + h * DD + dp] = f2bf(acc[r]);
            }
        }
    }
}

// ---------------------------------------------------------------------------
// K5: out = img + gelu(X @ W_in)   (bf16 MFMA, M=8192 N=768 K=768)
// grid: 64 m-blocks x 12 n-blocks (768); wave = 32m x 64n
// launch_bounds (256,3): 3 blocks/CU resident (no LDS), no tail.
// ---------------------------------------------------------------------------
__global__ __launch_bounds__(256, 3) void k_out(const short* __restrict__ Xb,
                                                const short* __restrict__ Wt,
                                                const float* __restrict__ img,
                                                float* __restrict__ out) {
    int mblk = blockIdx.x & 63, nblk = blockIdx.x >> 6;
    int wave = threadIdx.x >> 6, lane = threadIdx.x & 63;
    int quad = lane >> 4, c = lane & 15;
    int m0 = mblk * 128 + wave * 32;
    int n0 = nblk * 64;

    f32x4 acc[2][4];
#pragma unroll
    for (int t = 0; t < 2; t++)
#pragma unroll
        for (int u = 0; u < 4; u++) acc[t][u] = (f32x4){0.f, 0.f, 0.f, 0.f};

    for (int k0 = 0; k0 < HID; k0 += 32) {
        bf16x8 a[2], bfr[4];
#pragma unroll
        for (int t = 0; t < 2; t++)
            a[t] = *(const bf16x8*)(Xb + (size_t)(m0 + t * 16 + c) * HID + k0 + quad * 8);
#pragma unroll
        for (int u = 0; u < 4; u++)
            bfr[u] = *(const bf16x8*)(Wt + (size_t)(n0 + u * 16 + c) * HID + k0 + quad * 8);
#pragma unroll
        for (int t = 0; t < 2; t++)
#pragma unroll
            for (int u = 0; u < 4; u++)
                acc[t][u] = MFMA16B(a[t], bfr[u], acc[t][u]);
    }
#pragma unroll
    for (int t = 0; t < 2; t++) {
#pragma unroll
        for (int u = 0; u < 4; u++) {
#pragma unroll
            for (int r = 0; r < 4; r++) {
                int row = m0 + t * 16 + quad * 4 + r;
                int col = n0 + u * 16 + c;
                float x = acc[t][u][r];
                float g = 0.5f * x * (1.f + erff(x * 0.70710678118654752f));
                size_t o = (size_t)row * HID + col;
                out[o] = img[o] + g;
            }
        }
    }
}

// ---------------------------------------------------------------------------
// launch
// ---------------------------------------------------------------------------
extern "C" void kernel_launch(void* const* d_in, const int* in_sizes, int n_in,
                              void* d_out, int out_size, void* d_ws, size_t ws_size,
                              hipStream_t stream) {
    const float* img = (const float*)d_in[0];   // [8,1024,768]
    const float* txt = (const float*)d_in[1];   // [8,2048,768]
    const float* Win = (const float*)d_in[2];   // [768,768]
    const float* Wup = (const float*)d_in[3];   // [64,256]
    float* out = (float*)d_out;

    char* w = (char*)d_ws;
    short* Qs    = (short*)(w);                         // 96*2048*128*2 = 50331648
    short* Ks    = (short*)(w + 50331648);              // 96*1024*128*2 = 25165824
    short* Wt    = (short*)(w + 75497472);              // 768*768*2     = 1179648
    float* Lsum  = (float*)(w + 76677120);              // 96*2048*4     = 786432
    float* iattn = (float*)(w + 77463552);              // 96*1024*4     = 393216
    short* Wupb  = (short*)(w + 77856768);              // 16384*2       = 32768
    short* Xb    = (short*)(w);                         // aliases Qs (dead after k_attnacc)

    k_castq<<<dim3(6144), dim3(256), 0, stream>>>(txt, Qs);
    k_castk<<<dim3(3072), dim3(256), 0, stream>>>(img, Ks);
    k_castw<<<dim3(145), dim3(256), 0, stream>>>(Win, Wup, Wt, Wupb);
    hipMemsetAsync(iattn, 0, (size_t)BH * SS * sizeof(float), stream);
    k_lsum<<<dim3(768), dim3(256), 0, stream>>>(Qs, Ks, Lsum);
    k_attnacc<<<dim3(768), dim3(256), 0, stream>>>(Qs, Ks, Lsum, iattn);
    k_up<<<dim3(384), dim3(256), 0, stream>>>(img, iattn, Wupb, Xb);
    k_out<<<dim3(768), dim3(256), 0, stream>>>(Xb, Wt, img, out);
}

// Round 5
// 300.517 us; speedup vs baseline: 1.1526x; 1.1526x over previous
//
#include <hip/hip_runtime.h>
#include <cstdint>
#include <cstddef>

// ---------------------------------------------------------------------------
// Problem constants
// ---------------------------------------------------------------------------
#define BB    8      // batch
#define NH    12     // heads
#define BH    96     // BB*NH
#define SS    1024   // image tokens (32x32)
#define QQ    2048   // text tokens
#define DD    64     // head dim
#define HID   768
#define EDGE  32
#define KPOOL 16
#define POOLED 17

typedef short bf16x8 __attribute__((ext_vector_type(8)));
typedef _Float16 f16x8 __attribute__((ext_vector_type(8)));
typedef float f32x4  __attribute__((ext_vector_type(4)));

#define MFMA16B(a, b, c) __builtin_amdgcn_mfma_f32_16x16x32_bf16((a), (b), (c), 0, 0, 0)
#define MFMA16H(a, b, c) __builtin_amdgcn_mfma_f32_16x16x32_f16((a), (b), (c), 0, 0, 0)

// scores in base-2: Q pre-scaled by log2(e)/8 so exp(s/8) == exp2(score2)
#define QSCALE 0.18033688011112042f

#if __has_builtin(__builtin_amdgcn_exp2f)
#define EXP2(x) __builtin_amdgcn_exp2f(x)
#else
#define EXP2(x) exp2f(x)
#endif

__device__ __forceinline__ short f2bf(float x) {
    unsigned u = __builtin_bit_cast(unsigned, x);
    u = u + 0x7fffu + ((u >> 16) & 1u);          // RNE
    return (short)(u >> 16);
}
__device__ __forceinline__ short f2h(float x) {
    _Float16 h = (_Float16)x;                    // RNE
    return __builtin_bit_cast(short, h);
}
__device__ __forceinline__ f16x8 ash(bf16x8 v) {
    return __builtin_bit_cast(f16x8, v);
}

// ---------------------------------------------------------------------------
// Fragment-order layout for Qs/Ks:
//   rows grouped by 16 (group g, row-in-group c). Per group: 2048 shorts =
//   4 chunks of 512: ch0=hi,k[0:32) ch1=hi,k[32:64) ch2=lo,k[0:32) ch3=lo,k[32:64)
//   chunk internal: [quad(4)][c(16)][j(8)]  -> frag read = base + lane*8 shorts
// Q: fp16 hi/lo (both planes used). K: fp16 hi ONLY (lo chunks dead/unwritten)
// Score = (Qh+Ql)·Kh exactly; dropped error = Q·Kl ~ 2^-11 relative of K,
// ~4e-4 score noise — 11x below the bf16 config that flipped an argmax (r1).
// ---------------------------------------------------------------------------

// K0a: cast text -> Qs fragment-order (scaled by QSCALE), fp16 hi/lo
__global__ __launch_bounds__(256) void k_castq(const float* __restrict__ txt,
                                               short* __restrict__ Qs) {
    int i = blockIdx.x * 256 + threadIdx.x;
    int quad = i & 3, kh = (i >> 2) & 1;
    int row = i >> 3;                    // bh*2048 + q
    int c = row & 15, g = row >> 4;
    int q = row & 2047, bh = row >> 11;
    int b = bh / NH, h = bh - b * NH;
    const float* sp = txt + ((size_t)b * QQ + q) * HID + h * DD + kh * 32 + quad * 8;
    bf16x8 vh, vl;
#pragma unroll
    for (int j = 0; j < 8; j++) {
        float x = sp[j] * QSCALE;
        _Float16 hi = (_Float16)x;
        vh[j] = __builtin_bit_cast(short, hi);
        vl[j] = f2h(x - (float)hi);
    }
    short* dp = Qs + (size_t)g * 2048 + kh * 512 + quad * 128 + c * 8;
    *(bf16x8*)dp = vh;
    *(bf16x8*)(dp + 1024) = vl;
}

// K0b: cast image -> Ks fragment-order (unscaled), fp16 hi plane ONLY
__global__ __launch_bounds__(256) void k_castk(const float* __restrict__ img,
                                               short* __restrict__ Ks) {
    int i = blockIdx.x * 256 + threadIdx.x;
    int quad = i & 3, kh = (i >> 2) & 1;
    int row = i >> 3;                    // bh*1024 + s
    int c = row & 15, g = row >> 4;
    int s = row & 1023, bh = row >> 10;
    int b = bh / NH, h = bh - b * NH;
    const float* sp = img + ((size_t)b * SS + s) * HID + h * DD + kh * 32 + quad * 8;
    bf16x8 vh;
#pragma unroll
    for (int j = 0; j < 8; j++) {
        float x = sp[j];
        _Float16 hi = (_Float16)x;
        vh[j] = __builtin_bit_cast(short, hi);
    }
    short* dp = Ks + (size_t)g * 2048 + kh * 512 + quad * 128 + c * 8;
    *(bf16x8*)dp = vh;                   // lo chunks (dp+1024) never read — unwritten
}

// K0c: blocks 0..143: W_in [k][n] -> transposed bf16 Wt [n][k].
//      block 144: W_up [64][256] -> bf16 B-fragment order Wupb:
//      addr = (n>>4)*1024 + (k>>5)*512 + ((k>>3)&3)*128 + (n&15)*8 + (k&7)
__global__ __launch_bounds__(256) void k_castw(const float* __restrict__ W,
                                               const float* __restrict__ Wup,
                                               short* __restrict__ Wt,
                                               short* __restrict__ Wupb) {
    if (blockIdx.x == 144) {
        for (int i = threadIdx.x; i < 16384; i += 256) {
            int k = i >> 8, n = i & 255;
            int addr = (n >> 4) * 1024 + (k >> 5) * 512 + ((k >> 3) & 3) * 128
                     + (n & 15) * 8 + (k & 7);
            Wupb[addr] = f2bf(Wup[k * 256 + n]);
        }
        return;
    }
    __shared__ float T[64][65];
    int bx = blockIdx.x % 12, by = blockIdx.x / 12;
    for (int i = threadIdx.x; i < 4096; i += 256) {
        int r = i >> 6, cc = i & 63;
        T[r][cc] = W[(size_t)(by * 64 + r) * HID + bx * 64 + cc];
    }
    __syncthreads();
    for (int i = threadIdx.x; i < 4096; i += 256) {
        int r = i >> 6, cc = i & 63;
        Wt[(size_t)(bx * 64 + r) * HID + by * 64 + cc] = f2bf(T[cc][r]);
    }
}

// ---------------------------------------------------------------------------
// K1: Lsum[bh][q] = sum_s exp2(score2)
// fp16 single-plane both sides (Q-hi x K-hi): Lsum error averaged over 1024
// keys, far below argmax sensitivity. 2 MFMA per tile. (256,2) proven.
// ---------------------------------------------------------------------------
__global__ __launch_bounds__(256, 2) void k_lsum(const short* __restrict__ Qs,
                                                 const short* __restrict__ Ks,
                                                 float* __restrict__ Lsum) {
    __shared__ short Kt[2][4096];
    int bh = blockIdx.x % BH;
    int qblk = blockIdx.x / BH;          // [0,8)
    int tid = threadIdx.x;
    int w = tid >> 6, lane = tid & 63;
    int quad = lane >> 4, c = lane & 15;

    f16x8 a0[4], a1[4];
    const short* qbase = Qs + (size_t)bh * QQ * 128;
#pragma unroll
    for (int t = 0; t < 4; t++) {
        const short* ap = qbase + (size_t)(qblk * 16 + w * 4 + t) * 2048 + lane * 8;
        a0[t] = ash(*(const bf16x8*)(ap));
        a1[t] = ash(*(const bf16x8*)(ap + 512));
    }
    f32x4 lacc[4];
#pragma unroll
    for (int t = 0; t < 4; t++) lacc[t] = (f32x4){0.f, 0.f, 0.f, 0.f};

    const short* kbase = Ks + (size_t)bh * SS * 128;
    int sg = tid >> 7, so = tid & 127;   // staging: 2 groups per j-step (hi halves only)
    bf16x8 st[2];
#pragma unroll
    for (int j = 0; j < 2; j++)
        st[j] = *(const bf16x8*)(kbase + (size_t)(j * 2 + sg) * 2048 + so * 8);

    for (int t1 = 0; t1 < 16; t1++) {
        int buf = t1 & 1;
#pragma unroll
        for (int j = 0; j < 2; j++)
            *(bf16x8*)(&Kt[buf][j * 2048 + tid * 8]) = st[j];
        if (t1 + 1 < 16) {
#pragma unroll
            for (int j = 0; j < 2; j++)
                st[j] = *(const bf16x8*)(kbase + (size_t)((t1 + 1) * 4 + j * 2 + sg) * 2048 + so * 8);
        }
        __syncthreads();
#pragma unroll
        for (int g = 0; g < 4; g++) {
            const short* kp = &Kt[buf][g * 1024 + lane * 8];
            f16x8 kb0 = ash(*(const bf16x8*)(kp));
            f16x8 kb1 = ash(*(const bf16x8*)(kp + 512));
#pragma unroll
            for (int t = 0; t < 4; t++) {
                f32x4 acc = (f32x4){0.f, 0.f, 0.f, 0.f};
                acc = MFMA16H(a0[t], kb0, acc);
                acc = MFMA16H(a1[t], kb1, acc);
#pragma unroll
                for (int r = 0; r < 4; r++) lacc[t][r] += EXP2(acc[r]);
            }
        }
    }
#pragma unroll
    for (int t = 0; t < 4; t++) {
#pragma unroll
        for (int r = 0; r < 4; r++) {
            float v = lacc[t][r];
            v += __shfl_xor(v, 1);
            v += __shfl_xor(v, 2);
            v += __shfl_xor(v, 4);
            v += __shfl_xor(v, 8);
            if (c == 0)
                Lsum[(size_t)bh * QQ + qblk * 256 + w * 64 + t * 16 + quad * 4 + r] = v;
        }
    }
}

// ---------------------------------------------------------------------------
// K2: iattn[bh][s] += sum_{q half} exp2(score2)/Lsum[q]
// 4 MFMA/tile: Kh·(Qh+Ql) — K-lo term dropped (error ~4e-4 score noise,
// 11x below the r1 failure point). A-frags = K hi only (32 VGPR saved).
// ---------------------------------------------------------------------------
__global__ __launch_bounds__(256, 2) void k_attnacc(const short* __restrict__ Qs,
                                                    const short* __restrict__ Ks,
                                                    const float* __restrict__ Lsum,
                                                    float* __restrict__ iattn) {
    __shared__ short Qt[2][8192];
    int bh = blockIdx.x % BH;
    int rem = blockIdx.x / BH;           // [0,8)
    int sblk = rem >> 1, qh = rem & 1;
    int tid = threadIdx.x;
    int w = tid >> 6, lane = tid & 63;
    int quad = lane >> 4, c = lane & 15;

    f16x8 ah0[4], ah1[4];
    const short* kbase = Ks + (size_t)bh * SS * 128;
#pragma unroll
    for (int t = 0; t < 4; t++) {
        const short* ap = kbase + (size_t)(sblk * 16 + w * 4 + t) * 2048 + lane * 8;
        ah0[t] = ash(*(const bf16x8*)(ap));
        ah1[t] = ash(*(const bf16x8*)(ap + 512));
    }
    f32x4 racc[4];
#pragma unroll
    for (int t = 0; t < 4; t++) racc[t] = (f32x4){0.f, 0.f, 0.f, 0.f};

    const short* qbase = Qs + ((size_t)bh * QQ + qh * 1024) * 128;
    const float* lbase = Lsum + (size_t)bh * QQ + qh * 1024;

    bf16x8 st[4];
#pragma unroll
    for (int j = 0; j < 4; j++)
        st[j] = *(const bf16x8*)(qbase + (size_t)j * 2048 + tid * 8);

    for (int t2 = 0; t2 < 16; t2++) {
        int buf = t2 & 1;
#pragma unroll
        for (int j = 0; j < 4; j++)
            *(bf16x8*)(&Qt[buf][j * 2048 + tid * 8]) = st[j];
        if (t2 + 1 < 16) {
#pragma unroll
            for (int j = 0; j < 4; j++)
                st[j] = *(const bf16x8*)(qbase + (size_t)(t2 + 1) * 8192 + j * 2048 + tid * 8);
        }
        __syncthreads();
        float rl[4];
#pragma unroll
        for (int g = 0; g < 4; g++)
            rl[g] = __builtin_amdgcn_rcpf(lbase[t2 * 64 + g * 16 + c]);
#pragma unroll
        for (int g = 0; g < 4; g++) {
            const short* qp = &Qt[buf][g * 2048 + lane * 8];
            f16x8 qb0 = ash(*(const bf16x8*)(qp));
            f16x8 qb1 = ash(*(const bf16x8*)(qp + 512));
            f16x8 qb2 = ash(*(const bf16x8*)(qp + 1024));
            f16x8 qb3 = ash(*(const bf16x8*)(qp + 1536));
#pragma unroll
            for (int t = 0; t < 4; t++) {
                f32x4 acc = (f32x4){0.f, 0.f, 0.f, 0.f};
                acc = MFMA16H(ah0[t], qb0, acc);
                acc = MFMA16H(ah1[t], qb1, acc);
                acc = MFMA16H(ah0[t], qb2, acc);
                acc = MFMA16H(ah1[t], qb3, acc);
#pragma unroll
                for (int r = 0; r < 4; r++)
                    racc[t][r] = fmaf(EXP2(acc[r]), rl[g], racc[t][r]);
            }
        }
    }
#pragma unroll
    for (int t = 0; t < 4; t++) {
#pragma unroll
        for (int r = 0; r < 4; r++) {
            float v = racc[t][r];
            v += __shfl_xor(v, 1);
            v += __shfl_xor(v, 2);
            v += __shfl_xor(v, 4);
            v += __shfl_xor(v, 8);
            if (c == 0)
                atomicAdd(&iattn[(size_t)bh * SS + sblk * 256 + w * 64 + t * 16 + quad * 4 + r], v);
        }
    }
}

// ---------------------------------------------------------------------------
// K4: fused pool+argmax+region-gather+upsample GEMM (MFMA) + pixel-shuffle.
// grid: bh(96) x nq(4 oc-quarters). Block: pool argmax from iattn (redundant
// per nq — cheap), then region [256 pos x 64 d] staged bf16 A-frag order in
// LDS, W_up from Wupb B-frags, MFMA -> Xb bf16.
// ---------------------------------------------------------------------------
__global__ __launch_bounds__(256, 2) void k_up(const float* __restrict__ img,
                                               const float* __restrict__ iattn,
                                               const short* __restrict__ Wupb,
                                               short* __restrict__ Xb) {
    __shared__ short Reg[16384];         // 32 KB, aliased for pool phase
    float* F = (float*)Reg;
    float* Apool = F;                    // [1024]
    float* Vp = F + 1024;                // [544]
    float* bvp = F + 1568;               // [256]
    int*   bip = (int*)(F + 1824);       // [256]

    int bh = blockIdx.x >> 2, nq = blockIdx.x & 3;
    int b = bh / NH, h = bh - b * NH;
    int tid = threadIdx.x;
    int w = tid >> 6, lane = tid & 63;
    int quad = lane >> 4, c = lane & 15;

    // ---- pool + argmax (np first-max tiebreak) ----
    for (int i = tid; i < 1024; i += 256) Apool[i] = iattn[(size_t)bh * SS + i];
    __syncthreads();
    for (int i = tid; i < POOLED * EDGE; i += 256) {
        int r = i >> 5, cc = i & 31;
        float s = 0.f;
#pragma unroll
        for (int k = 0; k < KPOOL; k++) s += Apool[(r + k) * EDGE + cc];
        Vp[i] = s;
    }
    __syncthreads();
    float best = -1e30f;
    int bidx = 1 << 30;
    for (int i = tid; i < POOLED * POOLED; i += 256) {
        int r = i / POOLED, cc = i - r * POOLED;
        float s = 0.f;
#pragma unroll
        for (int k = 0; k < KPOOL; k++) s += Vp[r * EDGE + cc + k];
        if (s > best || (s == best && i < bidx)) { best = s; bidx = i; }
    }
    bvp[tid] = best;
    bip[tid] = bidx;
    __syncthreads();
    for (int off = 128; off; off >>= 1) {
        if (tid < off) {
            float ov = bvp[tid + off];
            int oi = bip[tid + off];
            if (ov > bvp[tid] || (ov == bvp[tid] && oi < bip[tid])) {
                bvp[tid] = ov;
                bip[tid] = oi;
            }
        }
        __syncthreads();
    }
    int widx = bip[0];
    __syncthreads();                     // all reads done before staging overwrites
    int r0 = widx / POOLED, c0 = widx - r0 * POOLED;

    // ---- stage region bf16 in A-fragment order ----
    // LDS addr for (pos,d): (pos>>4)*1024 + (d>>5)*512 + ((d>>3)&3)*128 + (pos&15)*8 + (d&7)
    for (int p = tid; p < 2048; p += 256) {
        int pos = p >> 3, sub = p & 7;   // sub -> d = sub*8..sub*8+7
        int gi = r0 + (pos >> 4), gj = c0 + (pos & 15);
        const float* sp = img + ((size_t)b * SS + gi * EDGE + gj) * HID + h * DD + sub * 8;
        bf16x8 v;
#pragma unroll
        for (int j = 0; j < 8; j++) v[j] = f2bf(sp[j]);
        *(bf16x8*)(&Reg[(pos >> 4) * 1024 + (sub >> 2) * 512 + (sub & 3) * 128 + (pos & 15) * 8]) = v;
    }
    __syncthreads();

    // ---- B-fragments (this block's 64 oc = 4 n-tiles) ----
    bf16x8 bu[4][2];
#pragma unroll
    for (int u = 0; u < 4; u++) {
#pragma unroll
        for (int kh = 0; kh < 2; kh++)
            bu[u][kh] = *(const bf16x8*)(Wupb + (nq * 4 + u) * 1024 + kh * 512 + lane * 8);
    }

    // ---- MFMA + pixel-shuffle epilogue ----
#pragma unroll
    for (int t = 0; t < 4; t++) {
        int g = w * 4 + t;               // pos group [0,16)
        bf16x8 a0 = *(const bf16x8*)(&Reg[g * 1024 + lane * 8]);
        bf16x8 a1 = *(const bf16x8*)(&Reg[g * 1024 + 512 + lane * 8]);
#pragma unroll
        for (int u = 0; u < 4; u++) {
            f32x4 acc = (f32x4){0.f, 0.f, 0.f, 0.f};
            acc = MFMA16B(a0, bu[u][0], acc);
            acc = MFMA16B(a1, bu[u][1], acc);
#pragma unroll
            for (int r = 0; r < 4; r++) {
                int pos = g * 16 + quad * 4 + r;
                int oc = nq * 64 + u * 16 + c;
                int i16 = pos >> 4, j16 = pos & 15;
                int a = oc >> 7, bbit = (oc >> 6) & 1, dp = oc & 63;
                int p2 = (2 * i16 + a) * EDGE + (2 * j16 + bbit);
                Xb[((size_t)b * SS + p2) * HID + h * DD + dp] = f2bf(acc[r]);
            }
        }
    }
}

// ---------------------------------------------------------------------------
// K5: out = img + gelu(X @ W_in)   (bf16 MFMA, M=8192 N=768 K=768)
// grid: 64 m-blocks x 12 n-blocks (768); wave = 32m x 64n
// ---------------------------------------------------------------------------
__global__ __launch_bounds__(256, 2) void k_out(const short* __restrict__ Xb,
                                                const short* __restrict__ Wt,
                                                const float* __restrict__ img,
                                                float* __restrict__ out) {
    int mblk = blockIdx.x & 63, nblk = blockIdx.x >> 6;
    int wave = threadIdx.x >> 6, lane = threadIdx.x & 63;
    int quad = lane >> 4, c = lane & 15;
    int m0 = mblk * 128 + wave * 32;
    int n0 = nblk * 64;

    f32x4 acc[2][4];
#pragma unroll
    for (int t = 0; t < 2; t++)
#pragma unroll
        for (int u = 0; u < 4; u++) acc[t][u] = (f32x4){0.f, 0.f, 0.f, 0.f};

    for (int k0 = 0; k0 < HID; k0 += 32) {
        bf16x8 a[2], bfr[4];
#pragma unroll
        for (int t = 0; t < 2; t++)
            a[t] = *(const bf16x8*)(Xb + (size_t)(m0 + t * 16 + c) * HID + k0 + quad * 8);
#pragma unroll
        for (int u = 0; u < 4; u++)
            bfr[u] = *(const bf16x8*)(Wt + (size_t)(n0 + u * 16 + c) * HID + k0 + quad * 8);
#pragma unroll
        for (int t = 0; t < 2; t++)
#pragma unroll
            for (int u = 0; u < 4; u++)
                acc[t][u] = MFMA16B(a[t], bfr[u], acc[t][u]);
    }
#pragma unroll
    for (int t = 0; t < 2; t++) {
#pragma unroll
        for (int u = 0; u < 4; u++) {
#pragma unroll
            for (int r = 0; r < 4; r++) {
                int row = m0 + t * 16 + quad * 4 + r;
                int col = n0 + u * 16 + c;
                float x = acc[t][u][r];
                float g = 0.5f * x * (1.f + erff(x * 0.70710678118654752f));
                size_t o = (size_t)row * HID + col;
                out[o] = img[o] + g;
            }
        }
    }
}

// ---------------------------------------------------------------------------
// launch
// ---------------------------------------------------------------------------
extern "C" void kernel_launch(void* const* d_in, const int* in_sizes, int n_in,
                              void* d_out, int out_size, void* d_ws, size_t ws_size,
                              hipStream_t stream) {
    const float* img = (const float*)d_in[0];   // [8,1024,768]
    const float* txt = (const float*)d_in[1];   // [8,2048,768]
    const float* Win = (const float*)d_in[2];   // [768,768]
    const float* Wup = (const float*)d_in[3];   // [64,256]
    float* out = (float*)d_out;

    char* w = (char*)d_ws;
    short* Qs    = (short*)(w);                         // 96*2048*128*2 = 50331648
    short* Ks    = (short*)(w + 50331648);              // 96*1024*128*2 = 25165824
    short* Wt    = (short*)(w + 75497472);              // 768*768*2     = 1179648
    float* Lsum  = (float*)(w + 76677120);              // 96*2048*4     = 786432
    float* iattn = (float*)(w + 77463552);              // 96*1024*4     = 393216
    short* Wupb  = (short*)(w + 77856768);              // 16384*2       = 32768
    short* Xb    = (short*)(w);                         // aliases Qs (dead after k_attnacc)

    k_castq<<<dim3(6144), dim3(256), 0, stream>>>(txt, Qs);
    k_castk<<<dim3(3072), dim3(256), 0, stream>>>(img, Ks);
    k_castw<<<dim3(145), dim3(256), 0, stream>>>(Win, Wup, Wt, Wupb);
    hipMemsetAsync(iattn, 0, (size_t)BH * SS * sizeof(float), stream);
    k_lsum<<<dim3(768), dim3(256), 0, stream>>>(Qs, Ks, Lsum);
    k_attnacc<<<dim3(768), dim3(256), 0, stream>>>(Qs, Ks, Lsum, iattn);
    k_up<<<dim3(384), dim3(256), 0, stream>>>(img, iattn, Wupb, Xb);
    k_out<<<dim3(768), dim3(256), 0, stream>>>(Xb, Wt, img, out);
}